// Round 7
// baseline (386.229 us; speedup 1.0000x reference)
//
#include <hip/hip_runtime.h>

// LaminiIndex v7b: out_k = softmax(Q K^T) K, out_v = softmax(Q K^T) V
// Q: 4096x128 fp32, K/V: 65536x128 fp32, outputs fp32 concat.
//
// Fixed-shift softmax exp(s-100) => split partials are plain sums.
// v7: producer-consumer wave specialization. Waves 0-3 (S-waves) compute
// S^T = K.Q^T (16x16x32 f16, one 16-key strip each -> no duplicate A loads),
// exp, pack P into a 2-group x 4-tile LDS ring. Waves 4-7 (O-waves) consume
// P (32x32x16 bf16) against fragment-packed K^T/V^T, 64 cols each. One
// barrier per 4-tile group; S produces group g while O consumes g-1 -> each
// SIMD holds 1 S-wave + 1 O-wave whose MFMA bursts interleave, keeping the
// matrix pipe fed through the other role's VALU/LDS phases. Divergent role
// loops with matched barrier counts share the register frame.
// v7b: __expf instead of __exp2f (glibc math.h macro collision on device).

typedef _Float16 f16x8  __attribute__((ext_vector_type(8)));
typedef short    s16x8  __attribute__((ext_vector_type(8)));
typedef float    f32x4  __attribute__((ext_vector_type(4)));
typedef float    f32x16 __attribute__((ext_vector_type(16)));

#define M_TOTAL 4096
#define N_TOTAL 65536
#define DDIM    128
#define BM      64
#define BN      64
#define NS      8      // key splits
#define GSZ     4      // tiles per barrier group

__device__ __forceinline__ unsigned int bf16_rne(float x) {
    unsigned int u = __float_as_uint(x);
    u += 0x7FFFu + ((u >> 16) & 1u);
    return u >> 16;
}

// One 64-key tile per block. K-blocks (bid<1024): Kfp = S-phase A-frags in
// 16x16x32 order (A[m=key][k=d]: m=lane&15, k=(lane>>4)*8+j), + KTp = O-phase
// B-frags in 32x32x16 order (B[k=key][n=d]: n=lane&31, k=8*(lane>>5)+j).
// V-blocks: VTp only.
__global__ void prep_kernel(const float* __restrict__ K, const float* __restrict__ V,
                            _Float16* __restrict__ Kfp,
                            unsigned short* __restrict__ KTp,
                            unsigned short* __restrict__ VTp) {
    __shared__ float tile[64 * 132];
    const int bid = blockIdx.x;
    const int isV = bid >> 10;
    const int t   = bid & 1023;
    const float* src = isV ? V : K;
    const int tid = threadIdx.x;
#pragma unroll
    for (int k = 0; k < 8; ++k) {                   // 64x128 fp32 in, coalesced
        int c   = tid + 256 * k;
        int row = c >> 5;
        int c4  = c & 31;
        float4 v = *(const float4*)(src + (size_t)(t * 64 + row) * DDIM + c4 * 4);
        *(float4*)&tile[row * 132 + c4 * 4] = v;
    }
    __syncthreads();

    unsigned short* Tp = isV ? VTp : KTp;
#pragma unroll
    for (int r = 0; r < 4; ++r) {                   // O B-frags: 1024 slots x 16B
        int c   = tid + 256 * r;
        int ln  = c & 63;
        int l31 = ln & 31, hh = ln >> 5;
        int dn  = c >> 8;                           // 32-col group
        int kk  = (c >> 6) & 3;                     // 16-key step
        int col = dn * 32 + l31;
        int k0  = kk * 16 + hh * 8;
        uint4 o;
        o.x = bf16_rne(tile[(k0 + 0) * 132 + col]) | (bf16_rne(tile[(k0 + 1) * 132 + col]) << 16);
        o.y = bf16_rne(tile[(k0 + 2) * 132 + col]) | (bf16_rne(tile[(k0 + 3) * 132 + col]) << 16);
        o.z = bf16_rne(tile[(k0 + 4) * 132 + col]) | (bf16_rne(tile[(k0 + 5) * 132 + col]) << 16);
        o.w = bf16_rne(tile[(k0 + 6) * 132 + col]) | (bf16_rne(tile[(k0 + 7) * 132 + col]) << 16);
        *(uint4*)(Tp + ((size_t)t * 1024 + c) * 8) = o;
    }
    if (!isV) {
#pragma unroll
        for (int r = 0; r < 4; ++r) {               // S A-frags (16x16 order)
            int c   = tid + 256 * r;
            int ln  = c & 63;
            int l15 = ln & 15, qd = ln >> 4;
            int kb  = c >> 8;                       // 16-key strip
            int kk  = (c >> 6) & 3;                 // 32-d step
            int row = kb * 16 + l15;                // key
            int d0  = kk * 32 + qd * 8;
            f16x8 f;
#pragma unroll
            for (int j = 0; j < 8; ++j) f[j] = (_Float16)tile[row * 132 + d0 + j];
            *(f16x8*)(Kfp + ((size_t)t * 1024 + c) * 8) = f;
        }
    }
}

// grid NS*64, 512 thr (8 waves: 4 S + 4 O; 1 of each per SIMD).
__global__ __launch_bounds__(512, 2)
void attn_kernel(const float* __restrict__ Q, const _Float16* __restrict__ Kfp,
                 const unsigned short* __restrict__ KTp, const unsigned short* __restrict__ VTp,
                 float* __restrict__ Okp, float* __restrict__ Ovp, float* __restrict__ Lp,
                 int iters) {
    __shared__ unsigned short p_lds[2][GSZ][BM * BN];   // 64KB P ring, XOR-swizzled
    __shared__ float l_red[4][BM];

    const int bid   = blockIdx.x;
    const int split = bid & (NS - 1);
    const int q0    = (bid >> 3) * BM;
    const int tid   = threadIdx.x;
    const int w     = tid >> 6;
    const int lane  = tid & 63;
    const int l15   = lane & 15, quad = lane >> 4;
    const int l31   = lane & 31, h    = lane >> 5;
    const int t0    = split * iters;
    const int NG    = iters / GSZ;

    if (w < 4) {
        // ================= S-waves (producers) =================
        const int kb = w;                            // 16-key strip
        // Q B-frags (16x16x32): qf[jt][kk] = Q[q0+jt*16+l15][kk*32+quad*8+j]
        f16x8 qf[4][4];
#pragma unroll
        for (int jt = 0; jt < 4; ++jt) {
            const float* qrow = Q + (size_t)(q0 + jt * 16 + l15) * DDIM + quad * 8;
#pragma unroll
            for (int kk = 0; kk < 4; ++kk) {
                float4 a = *(const float4*)(qrow + kk * 32);
                float4 b = *(const float4*)(qrow + kk * 32 + 4);
                f16x8 f;
                f[0] = (_Float16)a.x; f[1] = (_Float16)a.y; f[2] = (_Float16)a.z; f[3] = (_Float16)a.w;
                f[4] = (_Float16)b.x; f[5] = (_Float16)b.y; f[6] = (_Float16)b.z; f[7] = (_Float16)b.w;
                qf[jt][kk] = f;
            }
        }
        const _Float16* Ap = Kfp + (size_t)kb * 2048 + lane * 8;  // + t*8192 + kk*512
        float l0 = 0.f, l1 = 0.f, l2 = 0.f, l3 = 0.f;

        f16x8 af[4];
#pragma unroll
        for (int kk = 0; kk < 4; ++kk) af[kk] = *(const f16x8*)(Ap + (size_t)t0 * 8192 + kk * 512);

        for (int g = 0; g < NG; ++g) {
#pragma unroll
            for (int tt = 0; tt < GSZ; ++tt) {
                const size_t tn = (size_t)(t0 + g * GSZ + tt + 1) * 8192;
                f16x8 afn[4];                        // prefetch next tile's A
#pragma unroll
                for (int kk = 0; kk < 4; ++kk) afn[kk] = *(const f16x8*)(Ap + tn + kk * 512);

                f32x4 s[4];
                s[0] = 0.f; s[1] = 0.f; s[2] = 0.f; s[3] = 0.f;
#pragma unroll
                for (int kk = 0; kk < 4; ++kk)
#pragma unroll
                    for (int jt = 0; jt < 4; ++jt)
                        s[jt] = __builtin_amdgcn_mfma_f32_16x16x32_f16(af[kk], qf[jt][kk], s[jt], 0, 0, 0);

                // exp(s-100); C: col=l15 (q), row=quad*4+r (key in strip).
                // Pack b64 of 4 keys.
                unsigned short* pb = &p_lds[g & 1][tt][0];
                const int cch = kb * 2 + (quad >> 1);
#pragma unroll
                for (int jt = 0; jt < 4; ++jt) {
                    float p0 = __expf(s[jt][0] - 100.f);
                    float p1 = __expf(s[jt][1] - 100.f);
                    float p2 = __expf(s[jt][2] - 100.f);
                    float p3 = __expf(s[jt][3] - 100.f);
                    float ps = (p0 + p1) + (p2 + p3);
                    if (jt == 0) l0 += ps; else if (jt == 1) l1 += ps;
                    else if (jt == 2) l2 += ps; else l3 += ps;
                    unsigned int u0 = __float_as_uint(p0) + 0x8000u;
                    unsigned int u1 = __float_as_uint(p1) + 0x8000u;
                    unsigned int u2 = __float_as_uint(p2) + 0x8000u;
                    unsigned int u3 = __float_as_uint(p3) + 0x8000u;
                    uint2 pk;
                    pk.x = __builtin_amdgcn_perm(u1, u0, 0x07060302u);
                    pk.y = __builtin_amdgcn_perm(u3, u2, 0x07060302u);
                    int q = jt * 16 + l15;
                    *(uint2*)&pb[q * 64 + (cch ^ (q & 7)) * 8 + (quad & 1) * 4] = pk;
                }
#pragma unroll
                for (int kk = 0; kk < 4; ++kk) af[kk] = afn[kk];
            }
            __syncthreads();                         // phase g
        }
        __syncthreads();                             // phase NG (O drains last group)

        // l: fold 4 keys/lane -> strip: sum over quads (shfl), stash per strip.
        l0 += __shfl_xor(l0, 16, 64); l0 += __shfl_xor(l0, 32, 64);
        l1 += __shfl_xor(l1, 16, 64); l1 += __shfl_xor(l1, 32, 64);
        l2 += __shfl_xor(l2, 16, 64); l2 += __shfl_xor(l2, 32, 64);
        l3 += __shfl_xor(l3, 16, 64); l3 += __shfl_xor(l3, 32, 64);
        if (quad == 0) {
            l_red[kb][l15]      = l0;
            l_red[kb][16 + l15] = l1;
            l_red[kb][32 + l15] = l2;
            l_red[kb][48 + l15] = l3;
        }
    } else {
        // ================= O-waves (consumers) =================
        const int og = w & 3, mat = og >> 1, dpair = og & 1;     // 64 cols
        const unsigned short* Bp = (mat ? VTp : KTp) + (size_t)dpair * 4096 + lane * 8;

        f32x16 acc[2][2];                            // [qm][cb]: 64q x 64c
        acc[0][0] = 0.f; acc[0][1] = 0.f; acc[1][0] = 0.f; acc[1][1] = 0.f;

        s16x8 bfr[2][4];
#pragma unroll
        for (int cb = 0; cb < 2; ++cb)
#pragma unroll
            for (int kk = 0; kk < 4; ++kk)
                bfr[cb][kk] = *(const s16x8*)(Bp + (size_t)t0 * 8192 + (cb * 4 + kk) * 512);
        __syncthreads();                             // phase 0

        for (int g = 1; g <= NG; ++g) {
#pragma unroll
            for (int tt = 0; tt < GSZ; ++tt) {
                const size_t tn = (size_t)(t0 + (g - 1) * GSZ + tt + 1) * 8192;
                s16x8 bfn[2][4];                     // prefetch next tile's B
#pragma unroll
                for (int cb = 0; cb < 2; ++cb)
#pragma unroll
                    for (int kk = 0; kk < 4; ++kk)
                        bfn[cb][kk] = *(const s16x8*)(Bp + tn + (cb * 4 + kk) * 512);

                const unsigned short* pb = &p_lds[(g - 1) & 1][tt][0];
#pragma unroll
                for (int kk = 0; kk < 4; ++kk) {
                    s16x8 ap[2];
#pragma unroll
                    for (int qm = 0; qm < 2; ++qm) {
                        int q = qm * 32 + l31;
                        ap[qm] = *(const s16x8*)&pb[q * 64 + ((kk * 2 + h) ^ (q & 7)) * 8];
                    }
#pragma unroll
                    for (int cb = 0; cb < 2; ++cb)
#pragma unroll
                        for (int qm = 0; qm < 2; ++qm)
                            acc[qm][cb] = __builtin_amdgcn_mfma_f32_32x32x16_bf16(ap[qm], bfr[cb][kk], acc[qm][cb], 0, 0, 0);
                }
#pragma unroll
                for (int cb = 0; cb < 2; ++cb)
#pragma unroll
                    for (int kk = 0; kk < 4; ++kk) bfr[cb][kk] = bfn[cb][kk];
            }
            __syncthreads();                         // phase g
        }

        // O partial: C/D col=l31 (d), row=(r&3)+8*(r>>2)+4h (q).
        float* ob = (mat ? Ovp : Okp) + (size_t)split * (M_TOTAL * DDIM);
#pragma unroll
        for (int qm = 0; qm < 2; ++qm)
#pragma unroll
            for (int cb = 0; cb < 2; ++cb)
#pragma unroll
                for (int r = 0; r < 16; ++r) {
                    int q = q0 + qm * 32 + (r & 3) + 8 * (r >> 2) + 4 * h;
                    ob[(size_t)q * DDIM + dpair * 64 + cb * 32 + l31] = acc[qm][cb][r];
                }
    }

    __syncthreads();                                 // epilogue (uniform, both roles)
    if (tid < BM)
        Lp[(size_t)split * M_TOTAL + q0 + tid] =
            (l_red[0][tid] + l_red[1][tid]) + (l_red[2][tid] + l_red[3][tid]);
}

__global__ void combine_kernel(const float* __restrict__ Okp, const float* __restrict__ Ovp,
                               const float* __restrict__ Lp, float* __restrict__ out) {
    int i4 = blockIdx.x * 256 + threadIdx.x;        // float4 index, 131072 total
    int q  = i4 >> 5;
    float L = 0.f;
    float4 sk = make_float4(0.f, 0.f, 0.f, 0.f);
    float4 sv = make_float4(0.f, 0.f, 0.f, 0.f);
#pragma unroll
    for (int s = 0; s < NS; ++s) {
        L += Lp[(size_t)s * M_TOTAL + q];
        float4 a = ((const float4*)Okp)[(size_t)s * 131072 + i4];
        float4 b = ((const float4*)Ovp)[(size_t)s * 131072 + i4];
        sk.x += a.x; sk.y += a.y; sk.z += a.z; sk.w += a.w;
        sv.x += b.x; sv.y += b.y; sv.z += b.z; sv.w += b.w;
    }
    float inv = 1.f / L;
    ((float4*)out)[i4]          = make_float4(sk.x * inv, sk.y * inv, sk.z * inv, sk.w * inv);
    ((float4*)out)[131072 + i4] = make_float4(sv.x * inv, sv.y * inv, sv.z * inv, sv.w * inv);
}

extern "C" void kernel_launch(void* const* d_in, const int* in_sizes, int n_in,
                              void* d_out, int out_size, void* d_ws, size_t ws_size,
                              hipStream_t stream) {
    const float* Q = (const float*)d_in[0];
    const float* K = (const float*)d_in[1];
    const float* V = (const float*)d_in[2];
    float* out = (float*)d_out;

    // ws: Kfp 16MiB | KTp 16MiB | VTp 16MiB | Lp 8*16KB | Okp 8*2MiB | Ovp 8*2MiB = 80.1MB
    const size_t MB = 1024 * 1024;
    char* w0 = (char*)d_ws;
    _Float16*       Kfp = (_Float16*)w0;
    unsigned short* KTp = (unsigned short*)(w0 + 16 * MB);
    unsigned short* VTp = (unsigned short*)(w0 + 32 * MB);
    float*          Lp  = (float*)(w0 + 48 * MB);
    float*          Okp = (float*)(w0 + 48 * MB + (size_t)NS * 16384);
    float*          Ovp = Okp + (size_t)NS * (M_TOTAL * DDIM);

    prep_kernel<<<2048, 256, 0, stream>>>(K, V, Kfp, KTp, VTp);

    const int iters = N_TOTAL / (NS * BN);          // 128 tiles per block
    attn_kernel<<<NS * (M_TOTAL / BM), 512, 0, stream>>>(Q, Kfp, KTp, VTp, Okp, Ovp, Lp, iters);
    combine_kernel<<<(M_TOTAL * DDIM / 4) / 256, 256, 0, stream>>>(Okp, Ovp, Lp, out);
}